// Round 2
// baseline (125.131 us; speedup 1.0000x reference)
//
#include <hip/hip_runtime.h>
#include <math.h>

// LayerStatistics: out = (x copy [N floats], stats[5] = mean, sqmean, var(ddof=1), min, max)
// x: (32,64,128,128) fp32, N = 33554432. Memory-bound fused copy+reduce,
// single kernel with last-block-done final reduction.

constexpr int BLOCK = 256;
constexpr int GRID  = 2048;   // 256 CU * 8 blocks/CU; stride = 524288 (pow2)

typedef float v4f __attribute__((ext_vector_type(4)));

__global__ __launch_bounds__(BLOCK) void stats_fused(
    const v4f* __restrict__ in, v4f* __restrict__ out,
    float4* __restrict__ partials, unsigned int* __restrict__ counter,
    float* __restrict__ stats_out, int n4, double n_total)
{
    const int tid    = blockIdx.x * blockDim.x + threadIdx.x;
    const int stride = gridDim.x * blockDim.x;

    float s  = 0.0f;
    float ss = 0.0f;
    float mn =  INFINITY;
    float mx = -INFINITY;

    if ((n4 % (4 * stride)) == 0) {
        // fast path: 4 independent loads in flight per iteration
        for (int i = tid; i < n4; i += 4 * stride) {
            v4f v0 = in[i];
            v4f v1 = in[i + stride];
            v4f v2 = in[i + 2 * stride];
            v4f v3 = in[i + 3 * stride];
            __builtin_nontemporal_store(v0, &out[i]);
            __builtin_nontemporal_store(v1, &out[i + stride]);
            __builtin_nontemporal_store(v2, &out[i + 2 * stride]);
            __builtin_nontemporal_store(v3, &out[i + 3 * stride]);
            #pragma unroll
            for (int e = 0; e < 4; ++e) {
                float a0 = v0[e], a1 = v1[e], a2 = v2[e], a3 = v3[e];
                s  += (a0 + a1) + (a2 + a3);
                ss += (a0 * a0 + a1 * a1) + (a2 * a2 + a3 * a3);
                mn = fminf(mn, fminf(fminf(a0, a1), fminf(a2, a3)));
                mx = fmaxf(mx, fmaxf(fmaxf(a0, a1), fmaxf(a2, a3)));
            }
        }
    } else {
        for (int i = tid; i < n4; i += stride) {
            v4f v = in[i];
            __builtin_nontemporal_store(v, &out[i]);
            #pragma unroll
            for (int e = 0; e < 4; ++e) {
                float a = v[e];
                s  += a;
                ss += a * a;
                mn = fminf(mn, a);
                mx = fmaxf(mx, a);
            }
        }
    }

    // wave (64-lane) reduce
    #pragma unroll
    for (int off = 32; off > 0; off >>= 1) {
        s  += __shfl_down(s,  off, 64);
        ss += __shfl_down(ss, off, 64);
        mn = fminf(mn, __shfl_down(mn, off, 64));
        mx = fmaxf(mx, __shfl_down(mx, off, 64));
    }

    __shared__ float4 red[BLOCK / 64];
    const int lane = threadIdx.x & 63;
    const int wave = threadIdx.x >> 6;
    if (lane == 0) red[wave] = make_float4(s, ss, mn, mx);
    __syncthreads();

    __shared__ bool amLast;
    if (threadIdx.x == 0) {
        float4 a = red[0];
        #pragma unroll
        for (int w = 1; w < BLOCK / 64; ++w) {
            float4 b = red[w];
            a.x += b.x;
            a.y += b.y;
            a.z = fminf(a.z, b.z);
            a.w = fmaxf(a.w, b.w);
        }
        partials[blockIdx.x] = a;
        __threadfence();                       // release: partial visible device-wide
        unsigned int prev = atomicAdd(counter, 1u);
        amLast = (prev == gridDim.x - 1);
    }
    __syncthreads();

    if (!amLast) return;

    // last block: final reduction over GRID partials (double accumulation)
    __threadfence();                           // acquire
    double ds  = 0.0;
    double dss = 0.0;
    float  fmn =  INFINITY;
    float  fmx = -INFINITY;
    for (int i = threadIdx.x; i < GRID; i += BLOCK) {
        float4 p = partials[i];
        ds  += (double)p.x;
        dss += (double)p.y;
        fmn = fminf(fmn, p.z);
        fmx = fmaxf(fmx, p.w);
    }

    #pragma unroll
    for (int off = 32; off > 0; off >>= 1) {
        ds  += __shfl_down(ds,  off, 64);
        dss += __shfl_down(dss, off, 64);
        fmn = fminf(fmn, __shfl_down(fmn, off, 64));
        fmx = fmaxf(fmx, __shfl_down(fmx, off, 64));
    }

    __shared__ double sred[BLOCK / 64];
    __shared__ double ssred[BLOCK / 64];
    __shared__ float  mnred[BLOCK / 64];
    __shared__ float  mxred[BLOCK / 64];
    if (lane == 0) { sred[wave] = ds; ssred[wave] = dss; mnred[wave] = fmn; mxred[wave] = fmx; }
    __syncthreads();

    if (threadIdx.x == 0) {
        #pragma unroll
        for (int w = 1; w < BLOCK / 64; ++w) {
            ds  += sred[w];
            dss += ssred[w];
            fmn = fminf(fmn, mnred[w]);
            fmx = fmaxf(fmx, mxred[w]);
        }
        double mean   = ds / n_total;
        double sqmean = dss / n_total;
        double var    = (dss - ds * ds / n_total) / (n_total - 1.0);
        stats_out[0] = (float)mean;
        stats_out[1] = (float)sqmean;
        stats_out[2] = (float)var;
        stats_out[3] = fmn;
        stats_out[4] = fmx;
    }
}

extern "C" void kernel_launch(void* const* d_in, const int* in_sizes, int n_in,
                              void* d_out, int out_size, void* d_ws, size_t ws_size,
                              hipStream_t stream) {
    const float* x  = (const float*)d_in[0];
    float* out      = (float*)d_out;
    int n  = in_sizes[0];          // 33554432
    int n4 = n / 4;                // 8388608

    float4* partials      = (float4*)d_ws;                                  // GRID*16 B
    unsigned int* counter = (unsigned int*)((char*)d_ws + GRID * sizeof(float4));

    hipMemsetAsync(counter, 0, sizeof(unsigned int), stream);
    stats_fused<<<GRID, BLOCK, 0, stream>>>((const v4f*)x, (v4f*)out,
                                            partials, counter, out + n, n4, (double)n);
}